// Round 9
// baseline (1054.583 us; speedup 1.0000x reference)
//
#include <hip/hip_runtime.h>

#define LL 256
#define NEGV -1000000000.0f
#define LOG2E 1.4426950408889634f
#define LN2 0.6931471805599453f

// Compact triangular chart: row w holds its LL-w valid columns.
// off_of(w) = 256w - w(w-1)/2.  Chart = 32896 dwords.
__device__ __forceinline__ int off_of(int w) {
    return (w << 8) - ((w * (w - 1)) >> 1);
}

#define SHIFT_OFF 32896              // 4*256 floats (per-j shifts)
#define PART_OFF  (32896 + 1024)     // 4*256 floats (per-j cross-wave partials)
#define LDS_DWORDS (32896 + 2048)    // 34944 dw = 139776 B

// Fused F-step main sweep: steps wb..wb+FG-1 share L-reads over k in [FG, wb-1].
// k split across 16 waves (stride 16). Slots: cols {lane, lane+64, ...}.
template<int NC, int FG>
__device__ __forceinline__ void sweep(const float* chart, const float* shift,
                                      float* part, int wb, int wave, int lane) {
    float sum[NC][FG];
    float sh[NC][FG];
    #pragma unroll
    for (int q = 0; q < NC; ++q)
        #pragma unroll
        for (int j = 0; j < FG; ++j) {
            sum[q][j] = 0.f;
            sh[q][j] = shift[j * 256 + lane + 64 * q];
        }

    const int wbm1 = wb - 1;
    const int k0 = FG + wave;
    if (k0 <= wbm1) {
        int aL = off_of(k0) + lane;                 // L: row k, col lane(+64q)
        int aR = off_of(wb - k0) + k0 + lane;       // R(j=0): row wb-k, col lane+k
        int dL = 3976 - 16 * k0;                    // off(k+16)-off(k)
        int dR = 16 * (wb - k0) - 4216;             // off(wb-k-16)-off(wb-k)+16
        int e  = 256 - wb + k0;                     // off(a+1)-off(a), a=wb-k
        for (int k = k0; k <= wbm1; k += 16) {
            float lv[NC];
            #pragma unroll
            for (int q = 0; q < NC; ++q) lv[q] = chart[aL + 64 * q];
            int aj = aR, ej = e;
            #pragma unroll
            for (int j = 0; j < FG; ++j) {
                #pragma unroll
                for (int q = 0; q < NC; ++q) {
                    float r = chart[aj + 64 * q];
                    sum[q][j] += __builtin_amdgcn_exp2f(lv[q] + r - sh[q][j]);
                }
                aj += ej; ej -= 1;                  // off(a+j+1) = off(a+j) + (256-a-j)
            }
            aL += dL; dL -= 256;
            aR += dR; dR -= 256;
            e += 16;
        }
        #pragma unroll
        for (int q = 0; q < NC; ++q)
            #pragma unroll
            for (int j = 0; j < FG; ++j)
                atomicAdd(&part[j * 256 + lane + 64 * q], sum[q][j]);
    }
}

// Pre-phase: zero partials, compute per-(j,col) shift = mid-split probe
// (rows <= wb-1, stable). One thread per (j,col).
template<int FG>
__device__ __forceinline__ void prephase(const float* chart, float* shift,
                                         float* part, int wb, int tid) {
    if (tid < FG * 256) {
        part[tid] = 0.f;
        int col = tid & 255, j = tid >> 8;
        int wp = wb + j;
        if (col < LL - wp) {
            int km = wp >> 1;
            shift[tid] = chart[off_of(km) + col] + chart[off_of(wp - km) + col + km];
        }
    }
}

// Cleanup for step wp = wb+J: add boundary terms k in [1,FG-1] (old rows) and
// k in [wb, wb+J-1] (rows finalized by previous cleanups), then finalize row wp.
template<int FG, int J>
__device__ __forceinline__ void cleanup(float* chart, const float* shift,
                                        const float* part, int wb, int tid) {
    const int wp = wb + J;
    if (tid < LL - wp) {
        float shv = shift[J * 256 + tid];
        float tot = part[J * 256 + tid];
        #pragma unroll
        for (int k = 1; k <= FG - 1; ++k)
            tot += __builtin_amdgcn_exp2f(chart[off_of(k) + tid] +
                     chart[off_of(wp - k) + tid + k] - shv);
        #pragma unroll
        for (int m = 0; m < J; ++m) {
            int k = wb + m;
            tot += __builtin_amdgcn_exp2f(chart[off_of(k) + tid] +
                     chart[off_of(wp - k) + tid + k] - shv);
        }
        chart[off_of(wp) + tid] += shv + __builtin_amdgcn_logf(tot);
    }
}

__global__ __launch_bounds__(1024, 1)
void cyk_kernel(const float* __restrict__ s, const int* __restrict__ lens,
                float* __restrict__ out) {
    extern __shared__ float lds[];
    float* chart = lds;
    float* shift = lds + SHIFT_OFF;
    float* part  = lds + PART_OFF;

    const int b    = blockIdx.x;
    const int tid  = threadIdx.x;
    const int wave = tid >> 6;
    const int lane = tid & 63;
    const float* sb = s + (size_t)b * (LL * LL);

    // ---- init row 0 = NEG (read only if lens[b]==0) ----
    for (int i = tid; i < LL; i += 1024) chart[i] = NEGV * LOG2E;

    // ---- stage upper triangle of s_span[b] (×log2e), coalesced float4 ----
    for (int idx = tid; idx < (LL * LL) / 4; idx += 1024) {
        float4 v = reinterpret_cast<const float4*>(sb)[idx];
        int r  = (idx * 4) >> 8;
        int c0 = (idx * 4) & (LL - 1);
        float vv[4] = {v.x, v.y, v.z, v.w};
        #pragma unroll
        for (int q = 0; q < 4; ++q) {
            int w = (c0 + q) - r;
            if (w > 0) chart[off_of(w) + r] = vv[q] * LOG2E;
        }
    }
    __syncthreads();

    // ---- widths 2..5: tiny, sequential, thread-per-column ----
    for (int wp = 2; wp <= 5; ++wp) {
        if (tid < LL - wp) {
            float shv = chart[256 + tid] + chart[off_of(wp - 1) + tid + 1]; // k=1 term
            float tot = 0.f;
            for (int k = 1; k <= wp - 1; ++k)
                tot += __builtin_amdgcn_exp2f(chart[off_of(k) + tid] +
                         chart[off_of(wp - k) + tid + k] - shv);
            chart[off_of(wp) + tid] += shv + __builtin_amdgcn_logf(tot);
        }
        __syncthreads();
    }

    // ---- fused groups of 4: wb = 6,10,...,250 (steps 6..253) ----
    for (int wb = 6; wb <= 250; wb += 4) {
        const int NC = (LL - wb + 63) >> 6;
        prephase<4>(chart, shift, part, wb, tid);
        __syncthreads();
        switch (NC) {
            case 4: sweep<4, 4>(chart, shift, part, wb, wave, lane); break;
            case 3: sweep<3, 4>(chart, shift, part, wb, wave, lane); break;
            case 2: sweep<2, 4>(chart, shift, part, wb, wave, lane); break;
            default: sweep<1, 4>(chart, shift, part, wb, wave, lane); break;
        }
        __syncthreads();
        cleanup<4, 0>(chart, shift, part, wb, tid); __syncthreads();
        cleanup<4, 1>(chart, shift, part, wb, tid); __syncthreads();
        cleanup<4, 2>(chart, shift, part, wb, tid); __syncthreads();
        cleanup<4, 3>(chart, shift, part, wb, tid); __syncthreads();
    }

    // ---- tail group of 2: steps 254, 255 ----
    {
        const int wb = 254;
        prephase<2>(chart, shift, part, wb, tid);
        __syncthreads();
        sweep<1, 2>(chart, shift, part, wb, wave, lane);
        __syncthreads();
        cleanup<2, 0>(chart, shift, part, wb, tid); __syncthreads();
        cleanup<2, 1>(chart, shift, part, wb, tid); __syncthreads();
    }

    // ---- output ----
    if (tid == 0) {
        int len = lens[b];
        len = len < 0 ? 0 : (len > LL - 1 ? LL - 1 : len);
        out[b] = chart[off_of(len)] * LN2;
    }
}

extern "C" void kernel_launch(void* const* d_in, const int* in_sizes, int n_in,
                              void* d_out, int out_size, void* d_ws, size_t ws_size,
                              hipStream_t stream) {
    const float* s_span = (const float*)d_in[0];
    const int*   lens   = (const int*)d_in[1];
    float*       out    = (float*)d_out;
    const int B = in_sizes[1];               // 128
    const int lds_bytes = LDS_DWORDS * 4;    // 139776 B

    (void)hipFuncSetAttribute((const void*)cyk_kernel,
                              hipFuncAttributeMaxDynamicSharedMemorySize,
                              lds_bytes);

    cyk_kernel<<<B, 1024, lds_bytes, stream>>>(s_span, lens, out);
}

// Round 12
// 489.610 us; speedup vs baseline: 2.1539x; 2.1539x over previous
//
#include <hip/hip_runtime.h>

#define LL 256
#define NEGV -1000000000.0f
#define LOG2E 1.4426950408889634f
#define LN2 0.6931471805599453f

// Padded compact triangular chart: row w starts at poff(w), 16B-aligned;
// row length rounded up to 4 dwords. poff(256) = 33280 dwords.
__device__ __forceinline__ int poff(int w) {
    int t = w & 3;
    return (w << 8) - ((w * (w - 1)) >> 1) + 6 * (w >> 2) + ((t * (t - 1)) >> 1);
}

#define SHIFT_OFF 33280              // 256 floats
#define PART_OFF  33536              // 16*256 floats
#define LDS_DWORDS 37632             // 150528 B

// ---- sweeps: k strided by 16 across waves; lanes own ADJACENT columns ----
// part[wave*256 + c] gets this wave's partial sums (zeros if wave idle).

// w < 128 (ncols > 128): 4 cols/lane. L via aligned float4, R via 4 scalars.
__device__ __forceinline__ void sweep4(const float* chart, const float* shift,
                                       float* part, int w, int wave, int lane) {
    const int c0 = 4 * lane;
    float4 sh = *reinterpret_cast<const float4*>(&shift[c0]);
    float4 s = {0.f, 0.f, 0.f, 0.f};
    const int k0 = 1 + wave;
    if (k0 <= w - 1) {
        const float4* chart4 = reinterpret_cast<const float4*>(chart);
        int aL4 = (poff(k0) >> 2) + lane;       // float4 index (16B aligned)
        int aR  = poff(w - k0) + k0 + c0;
        int dL  = 4000 - 16 * k0;               // poff(k+16)-poff(k), mult of 16
        int dR  = 16 * (w - k0) - 4240;         // poff(a-16)-poff(a)+16, a=w-k
        for (int k = k0; k <= w - 1; k += 16) {
            float4 lv = chart4[aL4];
            float r0 = chart[aR], r1 = chart[aR + 1];
            float r2 = chart[aR + 2], r3 = chart[aR + 3];
            s.x += __builtin_amdgcn_exp2f(lv.x + r0 - sh.x);
            s.y += __builtin_amdgcn_exp2f(lv.y + r1 - sh.y);
            s.z += __builtin_amdgcn_exp2f(lv.z + r2 - sh.z);
            s.w += __builtin_amdgcn_exp2f(lv.w + r3 - sh.w);
            aL4 += (dL >> 2); dL -= 256;
            aR  += dR;        dR -= 256;
        }
    }
    *reinterpret_cast<float4*>(&part[wave * 256 + c0]) = s;
}

// 128 <= w < 192 (64 < ncols <= 128): 2 cols/lane (read2-mergeable pairs).
__device__ __forceinline__ void sweep2(const float* chart, const float* shift,
                                       float* part, int w, int wave, int lane) {
    const int c0 = 2 * lane;
    float sh0 = shift[c0], sh1 = shift[c0 + 1];
    float s0 = 0.f, s1 = 0.f;
    const int k0 = 1 + wave;
    if (k0 <= w - 1) {
        int aL = poff(k0) + c0;
        int aR = poff(w - k0) + k0 + c0;
        int dL = 4000 - 16 * k0;
        int dR = 16 * (w - k0) - 4240;
        for (int k = k0; k <= w - 1; k += 16) {
            float l0 = chart[aL], l1 = chart[aL + 1];
            float r0 = chart[aR], r1 = chart[aR + 1];
            s0 += __builtin_amdgcn_exp2f(l0 + r0 - sh0);
            s1 += __builtin_amdgcn_exp2f(l1 + r1 - sh1);
            aL += dL; dL -= 256;
            aR += dR; dR -= 256;
        }
    }
    part[wave * 256 + c0]     = s0;
    part[wave * 256 + c0 + 1] = s1;
}

// w >= 192 (ncols <= 64): 1 col/lane.
__device__ __forceinline__ void sweep1(const float* chart, const float* shift,
                                       float* part, int w, int wave, int lane) {
    float sh0 = shift[lane];
    float s0 = 0.f;
    const int k0 = 1 + wave;
    if (k0 <= w - 1) {
        int aL = poff(k0) + lane;
        int aR = poff(w - k0) + k0 + lane;
        int dL = 4000 - 16 * k0;
        int dR = 16 * (w - k0) - 4240;
        for (int k = k0; k <= w - 1; k += 16) {
            s0 += __builtin_amdgcn_exp2f(chart[aL] + chart[aR] - sh0);
            aL += dL; dL -= 256;
            aR += dR; dR -= 256;
        }
    }
    part[wave * 256 + lane] = s0;
}

__global__ __launch_bounds__(1024, 1)
void cyk_kernel(const float* __restrict__ s, const int* __restrict__ lens,
                float* __restrict__ out) {
    extern __shared__ float lds[];
    float* chart = lds;
    float* shift = lds + SHIFT_OFF;
    float* part  = lds + PART_OFF;

    const int b    = blockIdx.x;
    const int tid  = threadIdx.x;
    const int wave = tid >> 6;
    const int lane = tid & 63;
    const float* sb = s + (size_t)b * (LL * LL);

    // ---- init row 0 = NEG (read only if lens[b]==0) ----
    for (int i = tid; i < LL; i += 1024) chart[i] = NEGV * LOG2E;

    // ---- stage upper triangle of s_span[b] (×log2e), coalesced float4 ----
    for (int idx = tid; idx < (LL * LL) / 4; idx += 1024) {
        float4 v = reinterpret_cast<const float4*>(sb)[idx];
        int r  = (idx * 4) >> 8;
        int c0 = (idx * 4) & (LL - 1);
        float vv[4] = {v.x, v.y, v.z, v.w};
        #pragma unroll
        for (int q = 0; q < 4; ++q) {
            int w = (c0 + q) - r;
            if (w > 0) chart[poff(w) + r] = vv[q] * LOG2E;
        }
    }
    __syncthreads();

    // ---- bootstrap shift for w=2: the single k=1 term ----
    if (tid < LL - 2) shift[tid] = chart[256 + tid] + chart[256 + tid + 1];
    __syncthreads();

    // ---- DP over widths: 2 barriers/step ----
    for (int w = 2; w < LL; ++w) {
        const int ncols = LL - w;

        if (w < 128)      sweep4(chart, shift, part, w, wave, lane);
        else if (w < 192) sweep2(chart, shift, part, w, wave, lane);
        else              sweep1(chart, shift, part, w, wave, lane);
        __syncthreads();

        // combine 16 wave-partials; write row w; compute shift for width w+1
        if (tid < ncols) {
            float tot = 0.f;
            #pragma unroll
            for (int t = 0; t < 16; ++t) tot += part[t * 256 + tid];
            float newv = chart[poff(w) + tid] + shift[tid]
                       + __builtin_amdgcn_logf(tot);
            chart[poff(w) + tid] = newv;

            // shift for width w+1 (garbage for last col: unused)
            // probe A: split k=w -> left = just-written row w (register), right = row 1
            float p1 = newv + chart[256 + tid + w];
            float p2 = p1;
            if (w >= 3) {
                // probe B: mid split km=(w+1)>>1; rows <= w-1, stable
                int km = (w + 1) >> 1;
                p2 = chart[poff(km) + tid] + chart[poff(w + 1 - km) + tid + km];
            }
            shift[tid] = fmaxf(p1, p2);
        }
        __syncthreads();
    }

    // ---- output ----
    if (tid == 0) {
        int len = lens[b];
        len = len < 0 ? 0 : (len > LL - 1 ? LL - 1 : len);
        out[b] = chart[poff(len)] * LN2;
    }
}

extern "C" void kernel_launch(void* const* d_in, const int* in_sizes, int n_in,
                              void* d_out, int out_size, void* d_ws, size_t ws_size,
                              hipStream_t stream) {
    const float* s_span = (const float*)d_in[0];
    const int*   lens   = (const int*)d_in[1];
    float*       out    = (float*)d_out;
    const int B = in_sizes[1];               // 128
    const int lds_bytes = LDS_DWORDS * 4;    // 150528 B

    (void)hipFuncSetAttribute((const void*)cyk_kernel,
                              hipFuncAttributeMaxDynamicSharedMemorySize,
                              lds_bytes);

    cyk_kernel<<<B, 1024, lds_bytes, stream>>>(s_span, lens, out);
}